// Round 3
// baseline (1171.170 us; speedup 1.0000x reference)
//
#include <hip/hip_runtime.h>
#include <hip/hip_bf16.h>

#define IN_CH 512
#define OUT_CH 512
#define HW 64
#define BATCH 16
#define WEIGHT_GAIN 0.014731391274719739f    // 1/sqrt(512*9)
#define MOD_WEIGHT_GAIN 0.04419417382415922f // 1/sqrt(512)

typedef __attribute__((ext_vector_type(8))) short frag8;
typedef __attribute__((ext_vector_type(4))) float f32x4;

// ---------------- style[b][i] = (sum_j w[b][j]*mw[i][j])*g + mb[i] ----------------
__global__ void style_kernel(const float* __restrict__ w, const float* __restrict__ mw,
                             const float* __restrict__ mb, float* __restrict__ style) {
    const int gw = (blockIdx.x * 256 + threadIdx.x) >> 6;  // 0..8191
    const int lane = threadIdx.x & 63;
    const int b = gw >> 9;
    const int i = gw & 511;
    const float4* mwp = (const float4*)(mw + (size_t)i * 512 + lane * 8);
    const float4* wp  = (const float4*)(w + (size_t)b * 512 + lane * 8);
    float4 m0 = mwp[0], m1 = mwp[1];
    float4 w0 = wp[0],  w1 = wp[1];
    float s = m0.x * w0.x + m0.y * w0.y + m0.z * w0.z + m0.w * w0.w
            + m1.x * w1.x + m1.y * w1.y + m1.z * w1.z + m1.w * w1.w;
#pragma unroll
    for (int off = 32; off > 0; off >>= 1) s += __shfl_down(s, off, 64);
    if (lane == 0) style[(size_t)b * 512 + i] = s * MOD_WEIGHT_GAIN + mb[i];
}

// ---------------- wsq[o][i] = G^2 * sum_kk weight^2 ; wbf[kk][o][i] = bf16(weight) ----
__global__ void wprep_kernel(const float* __restrict__ weight, float* __restrict__ wsq,
                             __hip_bfloat16* __restrict__ wbf) {
    const int idx = blockIdx.x * 256 + threadIdx.x;   // 0..262143 = o*512+i
    const float* wp = weight + idx * 9;
    float s = 0.f;
#pragma unroll
    for (int kk = 0; kk < 9; ++kk) {
        float v = wp[kk];
        s += v * v;
        wbf[kk * 262144 + idx] = __float2bfloat16(v);
    }
    wsq[idx] = s * (WEIGHT_GAIN * WEIGHT_GAIN);
}

// ---------------- sc[b][o] = G * rsqrt(sum_i style^2 * wsq + 1e-8) -------------------
__global__ void demod_kernel(const float* __restrict__ style, const float* __restrict__ wsq,
                             float* __restrict__ sc) {
    const int gw = (blockIdx.x * 256 + threadIdx.x) >> 6;  // 0..8191
    const int lane = threadIdx.x & 63;
    const int b = gw >> 9;
    const int o = gw & 511;
    const float4* wq = (const float4*)(wsq + (size_t)o * 512 + lane * 8);
    const float4* st = (const float4*)(style + (size_t)b * 512 + lane * 8);
    float4 q0 = wq[0], q1 = wq[1];
    float4 s0 = st[0], s1 = st[1];
    float acc = q0.x * s0.x * s0.x + q0.y * s0.y * s0.y + q0.z * s0.z * s0.z + q0.w * s0.w * s0.w
              + q1.x * s1.x * s1.x + q1.y * s1.y * s1.y + q1.z * s1.z * s1.z + q1.w * s1.w * s1.w;
#pragma unroll
    for (int off = 32; off > 0; off >>= 1) acc += __shfl_down(acc, off, 64);
    if (lane == 0) sc[(size_t)b * 512 + o] = rsqrtf(acc + 1e-8f) * WEIGHT_GAIN;
}

// ---------------- conv: implicit GEMM, fused input transform ----------------
// Per block: 128 output pixels (2 rows) x 128 output channels, one batch.
// Per c0 (64 input ch): stage 4x66-pixel bf16 slab (style-folded, zero-padded)
// from fp32 NCHW x into LDS; A (weights) read per-fragment from global (L2-hot).
// 2 barriers per c0 -> 16 total. 4 waves x 4x4 16x16x32 MFMA tiles.
__launch_bounds__(256, 3)
__global__ void conv_kernel(const float* __restrict__ x,
                            const __hip_bfloat16* __restrict__ wbf,
                            const float* __restrict__ style,
                            const float* __restrict__ sc,
                            float* __restrict__ out) {
    // slab[p][ch] : p = r*66+cc (r=0..3 padded rows, cc=0..65 padded cols), 64 ch
    // chunk swizzle: 16B chunk g stored at ((g ^ (p&7))<<3) elements
    __shared__ __hip_bfloat16 slab[264 * 64];

    const int t = threadIdx.x;
    const int p0 = blockIdx.x * 128;   // 2 output rows: y0 = p0>>6
    const int m0 = blockIdx.y * 128;
    const int b  = blockIdx.z;
    const int y0 = blockIdx.x * 2;

    // staging mapping
    const int sp = t & 31;             // pixel-in-pass
    const int chunk = t >> 5;          // 8 channels per chunk

    // compute mapping
    const int wv = t >> 6;
    const int wm = (wv >> 1) * 64;
    const int wn = (wv & 1) * 64;
    const int lane = t & 63;
    const int ln15 = lane & 15;
    const int quad = lane >> 4;
    const int dy = wn >> 6;            // 0 or 1 (output row within tile)

    const __hip_bfloat16* abase = wbf + (m0 + wm + ln15) * 512 + quad * 8;
    const float* xb0 = x + (size_t)b * 512 * 4096;
    const short* slabp = (const short*)slab;

    f32x4 acc[4][4] = {};

    for (int c0 = 0; c0 < 512; c0 += 64) {
        // ---- stage slab: 264 pixels x 64 ch ----
        const int ch0 = c0 + chunk * 8;
        float st[8];
#pragma unroll
        for (int c = 0; c < 8; ++c) st[c] = style[b * 512 + ch0 + c];

        __syncthreads();   // previous c0's LDS reads done
#pragma unroll
        for (int pass = 0; pass < 9; ++pass) {
            const int p = pass * 32 + sp;
            const bool pv = (p < 264);
            const int r = p / 66;
            const int cc = p - r * 66;
            const int iy = y0 - 1 + r;
            const int ix = cc - 1;
            const bool valid = pv && (iy >= 0) && (iy < 64) && (ix >= 0) && (ix < 64);
            const int cy = min(max(iy, 0), 63);
            const int cx = min(max(ix, 0), 63);
            const float* xb = xb0 + ((size_t)ch0 * 64 + cy) * 64 + cx;
            union { __hip_bfloat16 h[8]; uint4 u[2]; } pk;
#pragma unroll
            for (int c = 0; c < 8; ++c) {
                float v = xb[(size_t)c * 4096];
                pk.h[c] = __float2bfloat16(valid ? v * st[c] : 0.f);
            }
            if (pv) {
                uint4* dst = (uint4*)(slab + p * 64 + ((chunk ^ (p & 7)) << 3));
                *dst = pk.u[0];
            }
            (void)pk.u[1];
        }
        __syncthreads();

        // ---- MFMA: 9 taps x 2 k-steps x 4x4 tiles ----
#pragma unroll
        for (int kk = 0; kk < 9; ++kk) {
            const int ky = kk / 3, kx = kk % 3;
            const __hip_bfloat16* asrc = abase + kk * 262144 + c0;
            frag8 af[2][4], bfr[2][4];
#pragma unroll
            for (int ks = 0; ks < 2; ++ks)
#pragma unroll
                for (int mt = 0; mt < 4; ++mt)
                    af[ks][mt] = *(const frag8*)(asrc + ks * 32 + mt * 8192);
#pragma unroll
            for (int ks = 0; ks < 2; ++ks) {
                const int gq = ks * 4 + quad;
#pragma unroll
                for (int nt = 0; nt < 4; ++nt) {
                    const int p = (dy + ky) * 66 + nt * 16 + ln15 + kx;
                    bfr[ks][nt] = *(const frag8*)(slabp + p * 64 + ((gq ^ (p & 7)) << 3));
                }
            }
#pragma unroll
            for (int mt = 0; mt < 4; ++mt)
#pragma unroll
                for (int nt = 0; nt < 4; ++nt)
#pragma unroll
                    for (int ks = 0; ks < 2; ++ks)
                        acc[mt][nt] = __builtin_amdgcn_mfma_f32_16x16x32_bf16(
                            af[ks][mt], bfr[ks][nt], acc[mt][nt], 0, 0, 0);
        }
    }

    // ---- epilogue: scale by G*demod[b][o], store fp32 NCHW ----
    const float* scb = sc + b * 512;
    float* outb = out + (size_t)b * 512 * 4096;
#pragma unroll
    for (int mt = 0; mt < 4; ++mt) {
        const int mrow = m0 + wm + mt * 16 + quad * 4;
#pragma unroll
        for (int v = 0; v < 4; ++v) {
            const float s = scb[mrow + v];
            float* orow = outb + (size_t)(mrow + v) * 4096 + p0 + wn + ln15;
#pragma unroll
            for (int nt = 0; nt < 4; ++nt)
                orow[nt * 16] = acc[mt][nt][v] * s;
        }
    }
}

extern "C" void kernel_launch(void* const* d_in, const int* in_sizes, int n_in,
                              void* d_out, int out_size, void* d_ws, size_t ws_size,
                              hipStream_t stream) {
    (void)in_sizes; (void)n_in; (void)out_size; (void)ws_size;
    const float* x      = (const float*)d_in[0];
    const float* w      = (const float*)d_in[1];
    const float* weight = (const float*)d_in[2];
    const float* mw     = (const float*)d_in[3];
    const float* mb     = (const float*)d_in[4];
    float* out = (float*)d_out;

    char* ws = (char*)d_ws;
    float* style         = (float*)(ws + 0);        //  32 KB
    float* sc            = (float*)(ws + 32768);    //  32 KB
    float* wsq           = (float*)(ws + 65536);    //   1 MB
    __hip_bfloat16* wbf  = (__hip_bfloat16*)(ws + 1114112);  // 4.5 MB  [9][512][512]

    wprep_kernel<<<dim3(1024), dim3(256), 0, stream>>>(weight, wsq, wbf);
    style_kernel<<<dim3(2048), dim3(256), 0, stream>>>(w, mw, mb, style);
    demod_kernel<<<dim3(2048), dim3(256), 0, stream>>>(style, wsq, sc);
    conv_kernel<<<dim3(32, 4, BATCH), dim3(256), 0, stream>>>(x, wbf, style, sc, out);
}